// Round 8
// baseline (193.971 us; speedup 1.0000x reference)
//
#include <hip/hip_runtime.h>
#include <hip/hip_bf16.h>

#define S_LEN 2048
#define EMB   1024
#define NH    16
#define HD    64
#define BATCH 2
#define MROWS (BATCH * S_LEN)   // 4096

typedef __attribute__((ext_vector_type(8))) short short8;   // 8 bf16 = 4 VGPR
typedef __attribute__((ext_vector_type(4))) float float4v;  // 4 fp32

#define MFMA16(a, b, c) __builtin_amdgcn_mfma_f32_16x16x32_bf16((a), (b), (c), 0, 0, 0)

typedef unsigned short u16;
typedef unsigned int   u32;

__device__ __forceinline__ u16 f2bf(float f) {
    union { float f; u32 u; } v; v.f = f;
    u32 u = v.u;
    return (u16)((u + 0x7fffu + ((u >> 16) & 1u)) >> 16);  // RNE
}

// packed fp32x2 -> bf16x2 (HW RNE on gfx950; fallback manual)
#if __has_builtin(__builtin_amdgcn_cvt_pk_bf16_f32)
typedef __attribute__((ext_vector_type(2))) __bf16 bfx2;
__device__ __forceinline__ u32 pkbf(float a, float b) {
    union { bfx2 v; u32 u; } c;
    c.v = __builtin_amdgcn_cvt_pk_bf16_f32(a, b);
    return c.u;
}
#else
__device__ __forceinline__ u32 pkbf(float a, float b) {
    return (u32)f2bf(a) | ((u32)f2bf(b) << 16);
}
#endif

#if __has_builtin(__builtin_amdgcn_exp2f)
#define EXP2(x) __builtin_amdgcn_exp2f(x)
#else
#define EXP2(x) exp2f(x)
#endif

// async 16B global->LDS (lds dest = wave-uniform base + lane*16)
typedef __attribute__((address_space(3))) unsigned char lds_u8;
typedef __attribute__((address_space(1))) const unsigned char glb_u8;
__device__ __forceinline__ void async_copy16(const void* g, void* l) {
    __builtin_amdgcn_global_load_lds((glb_u8*)g, (lds_u8*)l, 16, 0, 0);
}

// ---------------------------------------------------------------------------
// K0: fused prologue. z=0..3: convert+transpose weight z (Wq pre-scaled by
// 0.125*log2e so QK scores exit the MFMA in exp2 domain). z=4..7: x -> bf16.
// ---------------------------------------------------------------------------
__global__ __launch_bounds__(256) void prep_kernel(
    const float* __restrict__ x,
    const float* __restrict__ W0, const float* __restrict__ W1,
    const float* __restrict__ W2, const float* __restrict__ W3,
    u16* __restrict__ xb, u16* __restrict__ Wt) {
    const int z = blockIdx.z;
    const int tid = threadIdx.x;
    if (z >= 4) {
        int i = ((((z - 4) * 1024) + blockIdx.y * 32 + blockIdx.x) * 256 + tid) * 4;
        float4 f = *(const float4*)(x + i);
        uint2 o; o.x = pkbf(f.x, f.y); o.y = pkbf(f.z, f.w);
        *(uint2*)(xb + i) = o;
        return;
    }
    const float* W = (z == 0) ? W0 : (z == 1) ? W1 : (z == 2) ? W2 : W3;
    u16* dst = Wt + (size_t)z * EMB * EMB;
    const float sc = (z == 0) ? 0.18033688011112042f : 1.0f;
    __shared__ float tile[32][33];
    int c0 = blockIdx.x * 32, r0 = blockIdx.y * 32;
    int tx = tid & 31, ty = tid >> 5;
#pragma unroll
    for (int i = 0; i < 4; ++i)
        tile[ty + 8 * i][tx] = W[(size_t)(r0 + ty + 8 * i) * EMB + c0 + tx];
    __syncthreads();
#pragma unroll
    for (int i = 0; i < 4; ++i)
        dst[(size_t)(c0 + ty + 8 * i) * EMB + r0 + tx] = f2bf(tile[tx][ty + 8 * i] * sc);
}

// ---------------------------------------------------------------------------
// GEMM core (128x128): BK=32, depth-1 LDS double-buffer, xor swizzle
// s(row)=(row>>1)&3 (2-way on banks = free). Prefetch before MFMAs.
// ---------------------------------------------------------------------------
#define GEMM_STEP(B, KN)                                                                       \
    {                                                                                           \
        short8 a[4], b[4];                                                                      \
        _Pragma("unroll")                                                                       \
        for (int i = 0; i < 4; ++i) a[i] = *(const short8*)&As[B][wm * 64 + i * 16 + l15][ca];  \
        _Pragma("unroll")                                                                       \
        for (int j = 0; j < 4; ++j) b[j] = *(const short8*)&Bs[B][wn * 64 + j * 16 + l15][ca];  \
        if ((KN) < EMB) {                                                                       \
            for (int wl = wid; wl < 8; wl += 4) {                                               \
                async_copy16(&Ag[(size_t)(m0 + wl * 16 + rr) * EMB + (KN) + cc], &As[B ^ 1][wl * 16][0]); \
                async_copy16(&Bg[(size_t)(n0 + wl * 16 + rr) * EMB + (KN) + cc], &Bs[B ^ 1][wl * 16][0]); \
            }                                                                                   \
        }                                                                                       \
        _Pragma("unroll")                                                                       \
        for (int i = 0; i < 4; ++i)                                                             \
            _Pragma("unroll")                                                                   \
            for (int j = 0; j < 4; ++j)                                                         \
                acc[i][j] = MFMA16(a[i], b[j], acc[i][j]);                                      \
        __syncthreads();                                                                        \
    }

#define GEMM_CORE(A_, B_)                                                                      \
    const int tid = threadIdx.x;                                                                \
    const int lane = tid & 63, wid = tid >> 6;                                                  \
    const int wm = wid >> 1, wn = wid & 1;                                                      \
    const int l15 = lane & 15, lq = lane >> 4;                                                  \
    const int m0 = blockIdx.y * 128, n0 = blockIdx.x * 128;                                     \
    const u16* Ag = (A_);                                                                       \
    const u16* Bg = (B_);                                                                       \
    __shared__ u16 As[2][128][32];                                                              \
    __shared__ u16 Bs[2][128][32];                                                              \
    float4v acc[4][4] = {};                                                                     \
    const int rr = lane >> 2;                                                                   \
    const int cc = ((lane & 3) ^ ((rr >> 1) & 3)) * 8;                                          \
    const int ca = (lq ^ ((l15 >> 1) & 3)) * 8;                                                 \
    for (int wl = wid; wl < 8; wl += 4) {                                                       \
        async_copy16(&Ag[(size_t)(m0 + wl * 16 + rr) * EMB + cc], &As[0][wl * 16][0]);          \
        async_copy16(&Bg[(size_t)(n0 + wl * 16 + rr) * EMB + cc], &Bs[0][wl * 16][0]);          \
    }                                                                                           \
    __syncthreads();                                                                            \
    for (int k0 = 0; k0 < EMB; k0 += 64) {                                                      \
        GEMM_STEP(0, k0 + 32)                                                                   \
        GEMM_STEP(1, k0 + 64)                                                                   \
    }

// K2: fused 3-projection GEMM: z=0 Q[B,H,S,D], z=1 K[B,H,S,D], z=2 V^T[B,H,D,S]
__global__ __launch_bounds__(256) void gemm_proj_kernel(
    const u16* __restrict__ A, const u16* __restrict__ WtAll,
    u16* __restrict__ Qb, u16* __restrict__ Kb, u16* __restrict__ Vtb) {
    const int z = blockIdx.z;
    const u16* Wt = WtAll + (size_t)z * EMB * EMB;
    GEMM_CORE(A, Wt)
#pragma unroll
    for (int i = 0; i < 4; ++i)
#pragma unroll
        for (int j = 0; j < 4; ++j) {
            int mb = m0 + wm * 64 + i * 16 + lq * 4;      // 4 consecutive m
            int n  = n0 + wn * 64 + j * 16 + l15;
            int b_ = mb >> 11, s = mb & 2047;
            int h = n >> 6, d = n & 63;
            if (z == 2) {
                uint2 pv;
                pv.x = pkbf(acc[i][j][0], acc[i][j][1]);
                pv.y = pkbf(acc[i][j][2], acc[i][j][3]);
                *(uint2*)&Vtb[(((size_t)(b_ * NH + h) * HD + d) * S_LEN) + s] = pv;
            } else {
                u16* dst = (z == 1) ? Kb : Qb;
#pragma unroll
                for (int r = 0; r < 4; ++r)
                    dst[(((size_t)(b_ * NH + h) * S_LEN + s + r) * HD) + d] = f2bf(acc[i][j][r]);
            }
        }
}

// ---------------------------------------------------------------------------
// K4: output GEMM -> fp32. 128m x 64n tiles: grid (16,32) = 512 blocks.
// ---------------------------------------------------------------------------
__global__ __launch_bounds__(256) void gemm_out_kernel(
    const u16* __restrict__ A, const u16* __restrict__ Wt, float* __restrict__ out) {
    const int tid = threadIdx.x;
    const int lane = tid & 63, wid = tid >> 6;
    const int wm = wid >> 1, wn = wid & 1;
    const int l15 = lane & 15, lq = lane >> 4;
    const int m0 = blockIdx.y * 128, n0 = blockIdx.x * 64;
    __shared__ u16 As[2][128][32];
    __shared__ u16 Bs[2][64][32];
    float4v acc[4][2] = {};
    const int rr = lane >> 2;
    const int cc = ((lane & 3) ^ ((rr >> 1) & 3)) * 8;
    const int ca = (lq ^ ((l15 >> 1) & 3)) * 8;

#define GO_STAGE(B, KN)                                                                        \
    {                                                                                           \
        for (int wl = wid; wl < 8; wl += 4)                                                     \
            async_copy16(&A[(size_t)(m0 + wl * 16 + rr) * EMB + (KN) + cc], &As[B][wl * 16][0]);\
        async_copy16(&Wt[(size_t)(n0 + wid * 16 + rr) * EMB + (KN) + cc], &Bs[B][wid * 16][0]); \
    }
#define GO_STEP(B, KN)                                                                         \
    {                                                                                           \
        short8 a[4], b[2];                                                                      \
        _Pragma("unroll")                                                                       \
        for (int i = 0; i < 4; ++i) a[i] = *(const short8*)&As[B][wm * 64 + i * 16 + l15][ca];  \
        _Pragma("unroll")                                                                       \
        for (int j = 0; j < 2; ++j) b[j] = *(const short8*)&Bs[B][wn * 32 + j * 16 + l15][ca];  \
        if ((KN) < EMB) GO_STAGE(B ^ 1, KN)                                                     \
        _Pragma("unroll")                                                                       \
        for (int i = 0; i < 4; ++i)                                                             \
            _Pragma("unroll")                                                                   \
            for (int j = 0; j < 2; ++j)                                                         \
                acc[i][j] = MFMA16(a[i], b[j], acc[i][j]);                                      \
        __syncthreads();                                                                        \
    }

    GO_STAGE(0, 0)
    __syncthreads();
    for (int k0 = 0; k0 < EMB; k0 += 64) {
        GO_STEP(0, k0 + 32)
        GO_STEP(1, k0 + 64)
    }
#pragma unroll
    for (int i = 0; i < 4; ++i)
#pragma unroll
        for (int j = 0; j < 2; ++j)
#pragma unroll
            for (int r = 0; r < 4; ++r) {
                int m = m0 + wm * 64 + i * 16 + lq * 4 + r;
                int n = n0 + wn * 32 + j * 16 + l15;
                out[(size_t)m * EMB + n] = acc[i][j][r];
            }
}

// ---------------------------------------------------------------------------
// K3: flash attention (causal), S^T = K*Q^T, fixed-shift softmax (m=0),
// QUAD-PHASE: each block owns q-tiles {bx, 15-bx, 16+bx, 31-bx} (uniform 66
// tile-units) sharing ONE K/V stream. Per iteration a wave runs 4 independent
// QK->softmax->PV streams against one kf/vf load -> 4-way ILP hides ds/MFMA/
// exp2 latency at 1 wave/SIMD, and fixed costs amortize over 256 q-rows.
// 4-deep K/V ring, one barrier per 2 kv-tiles (literal slots; staging has ~2
// iterations of lead time so the barrier vmcnt drain is covered).
// Grid (8,32)=256 = 1 block/CU. LDS 98.8 KB. launch_bounds(256,1): VGPRs free.
// ---------------------------------------------------------------------------
#define ATTN_STAGE(B, T)                                                                       \
    {                                                                                           \
        int kv0s = (T) * 64;                                                                    \
        for (int wl = wid; wl < 8; wl += 4) {                                                   \
            async_copy16(&Kb[(size_t)(kv0s + wl * 8 + rr8) * HD + cc8], &Ks[B][wl * 8][0]);     \
            async_copy16(&Vb[(size_t)(wl * 8 + rr8) * S_LEN + kv0s + cc8], &Vs[B][wl * 8][0]);  \
        }                                                                                       \
    }

// QK + mask + exp2 + pack + write (no drain, no PV)
#define ATTN_QKSM(KF, T, QF, PS, QW)                                                           \
    {                                                                                           \
        const int kv0 = (T) * 64;                                                               \
        float4v sc[4];                                                                          \
        _Pragma("unroll")                                                                       \
        for (int nt = 0; nt < 4; ++nt) {                                                        \
            float4v c4 = {};                                                                    \
            c4 = MFMA16(KF[nt][0], QF[0], c4);                                                  \
            c4 = MFMA16(KF[nt][1], QF[1], c4);                                                  \
            sc[nt] = c4;                                                                        \
        }                                                                                       \
        if (kv0 + 63 > (QW)) {                                                                  \
            const int qi = (QW) + l15;                                                          \
            _Pragma("unroll")                                                                   \
            for (int nt = 0; nt < 4; ++nt)                                                      \
                _Pragma("unroll")                                                               \
                for (int r = 0; r < 4; ++r)                                                     \
                    if (kv0 + nt * 16 + lq * 4 + r > qi) sc[nt][r] = -__builtin_inff();         \
        }                                                                                       \
        _Pragma("unroll")                                                                       \
        for (int nt = 0; nt < 4; ++nt) {                                                        \
            float p0 = EXP2(sc[nt][0]);                                                         \
            float p1 = EXP2(sc[nt][1]);                                                         \
            float p2 = EXP2(sc[nt][2]);                                                         \
            float p3 = EXP2(sc[nt][3]);                                                         \
            uint2 pk;                                                                           \
            pk.x = pkbf(p0, p1);                                                                \
            pk.y = pkbf(p2, p3);                                                                \
            *(uint2*)&PS[wid][l15][nt * 16 + lq * 4] = pk;                                      \
        }                                                                                       \
    }

#define ATTN_PV(PS, VF, OO, LS)                                                                \
    {                                                                                           \
        _Pragma("unroll")                                                                       \
        for (int kk = 0; kk < 2; ++kk) {                                                        \
            short8 pf = *(const short8*)&PS[wid][l15][kk * 32 + lq * 8];                        \
            _Pragma("unroll")                                                                   \
            for (int nd = 0; nd < 4; ++nd)                                                      \
                OO[nd] = MFMA16(pf, VF[kk][nd], OO[nd]);                                        \
            LS = MFMA16(pf, ones8, LS);                                                         \
        }                                                                                       \
    }

#define ATTN_ITER(B, T)                                                                        \
    {                                                                                           \
        short8 kf[4][2];                                                                        \
        _Pragma("unroll")                                                                       \
        for (int nt = 0; nt < 4; ++nt) {                                                        \
            int r_ = nt * 16 + l15;                                                             \
            int sw = r_ & 7;                                                                    \
            kf[nt][0] = *(const short8*)&Ks[B][r_][(lq ^ sw) * 8];                              \
            kf[nt][1] = *(const short8*)&Ks[B][r_][((lq + 4) ^ sw) * 8];                        \
        }                                                                                       \
        const bool a0_ = ((T) * 64 <= qw0 + 15);                                                \
        const bool a1_ = ((T) * 64 <= qw1 + 15);                                                \
        const bool a2_ = ((T) * 64 <= qw2 + 15);                                                \
        if (a0_) ATTN_QKSM(kf, T, qf0, Ps0, qw0)                                                \
        if (a1_) ATTN_QKSM(kf, T, qf1, Ps1, qw1)                                                \
        if (a2_) ATTN_QKSM(kf, T, qf2, Ps2, qw2)                                                \
        ATTN_QKSM(kf, T, qf3, Ps3, qw3)                                                         \
        short8 vf[2][4];                                                                        \
        _Pragma("unroll")                                                                       \
        for (int kk = 0; kk < 2; ++kk)                                                          \
            _Pragma("unroll")                                                                   \
            for (int nd = 0; nd < 4; ++nd) {                                                    \
                int d = nd * 16 + l15;                                                          \
                vf[kk][nd] = *(const short8*)&Vs[B][d][((kk * 4 + lq) ^ (d & 7)) * 8];          \
            }                                                                                   \
        asm volatile("s_waitcnt lgkmcnt(0)" ::: "memory");                                      \
        if (a0_) ATTN_PV(Ps0, vf, O0, ls0)                                                     \
        if (a1_) ATTN_PV(Ps1, vf, O1, ls1)                                                     \
        if (a2_) ATTN_PV(Ps2, vf, O2, ls2)                                                     \
        ATTN_PV(Ps3, vf, O3, ls3)                                                              \
    }

#define ATTN_EPI(OO, LS, Q0)                                                                   \
    {                                                                                           \
        _Pragma("unroll")                                                                       \
        for (int r = 0; r < 4; ++r) {                                                           \
            float lr = 1.f / LS[r];                                                             \
            int s = (Q0) + wid * 16 + lq * 4 + r;                                               \
            size_t base = ((size_t)b * S_LEN + s) * EMB + h * HD;                               \
            _Pragma("unroll")                                                                   \
            for (int nd = 0; nd < 4; ++nd)                                                      \
                ctx[base + nd * 16 + l15] = f2bf(OO[nd][r] * lr);                               \
        }                                                                                       \
    }

__global__ __launch_bounds__(256, 1) void attn_kernel(
    const u16* __restrict__ Q, const u16* __restrict__ K,
    const u16* __restrict__ Vt, u16* __restrict__ ctx) {
    const int tid = threadIdx.x;
    const int lane = tid & 63, wid = tid >> 6;
    const int l15 = lane & 15, lq = lane >> 4;
    const int bh = blockIdx.y;
    const int b = bh >> 4, h = bh & 15;
    const int bx = blockIdx.x;  // [0,8)

    const u16* Qb = Q + (size_t)bh * S_LEN * HD;
    const u16* Kb = K + (size_t)bh * S_LEN * HD;
    const u16* Vb = Vt + (size_t)bh * HD * S_LEN;

    __shared__ u16 Ks[4][64][64];    // ring [kv][d], xor-swizzled (32 KB)
    __shared__ u16 Vs[4][64][64];    // ring [d][kv], xor-swizzled (32 KB)
    __shared__ u16 Ps0[4][16][68];   // per-wave P scratch, phase 0..3
    __shared__ u16 Ps1[4][16][68];
    __shared__ u16 Ps2[4][16][68];
    __shared__ u16 Ps3[4][16][68];

    const int rr8 = lane >> 3;
    const int cc8 = ((lane & 7) ^ rr8) * 8;  // s(row)=row&7

    // 4 q-tiles per block: uniform 66 tile-units
    const int qt0 = bx, qt1 = 15 - bx, qt2 = 16 + bx, qt3 = 31 - bx;
    const int qw0 = qt0 * 64 + wid * 16;
    const int qw1 = qt1 * 64 + wid * 16;
    const int qw2 = qt2 * 64 + wid * 16;
    const int qw3 = qt3 * 64 + wid * 16;

    // ones column for MFMA row-sum (bf16 1.0 = 0x3F80)
    short8 ones8;
#pragma unroll
    for (int i = 0; i < 8; ++i) ones8[i] = (short)0x3F80;

    // Q fragments (B-operand layout: lane n=l15 q-row, k=lq*8+j)
    short8 qf0[2], qf1[2], qf2[2], qf3[2];
#pragma unroll
    for (int ks = 0; ks < 2; ++ks) {
        qf0[ks] = *(const short8*)&Qb[(size_t)(qw0 + l15) * HD + ks * 32 + lq * 8];
        qf1[ks] = *(const short8*)&Qb[(size_t)(qw1 + l15) * HD + ks * 32 + lq * 8];
        qf2[ks] = *(const short8*)&Qb[(size_t)(qw2 + l15) * HD + ks * 32 + lq * 8];
        qf3[ks] = *(const short8*)&Qb[(size_t)(qw3 + l15) * HD + ks * 32 + lq * 8];
    }

    float4v O0[4] = {}, O1[4] = {}, O2[4] = {}, O3[4] = {};
    float4v ls0 = {}, ls1 = {}, ls2 = {}, ls3 = {};

    const int ntiles = 32 - bx;  // phase-3 bound (superset of the others)
    ATTN_STAGE(0, 0)
    ATTN_STAGE(1, 1)
    __syncthreads();
    for (int t = 0; t < ntiles; t += 4) {
        if (t + 2 < ntiles) ATTN_STAGE(2, t + 2)
        if (t + 3 < ntiles) ATTN_STAGE(3, t + 3)
        ATTN_ITER(0, t)
        if (t + 1 < ntiles) ATTN_ITER(1, t + 1)
        __syncthreads();
        if (t + 2 < ntiles) {
            if (t + 4 < ntiles) ATTN_STAGE(0, t + 4)
            if (t + 5 < ntiles) ATTN_STAGE(1, t + 5)
            ATTN_ITER(2, t + 2)
            if (t + 3 < ntiles) ATTN_ITER(3, t + 3)
        }
        __syncthreads();
    }

    ATTN_EPI(O0, ls0, qt0 * 64)
    ATTN_EPI(O1, ls1, qt1 * 64)
    ATTN_EPI(O2, ls2, qt2 * 64)
    ATTN_EPI(O3, ls3, qt3 * 64)
}

// ---------------------------------------------------------------------------
extern "C" void kernel_launch(void* const* d_in, const int* in_sizes, int n_in,
                              void* d_out, int out_size, void* d_ws, size_t ws_size,
                              hipStream_t stream) {
    const float* x  = (const float*)d_in[0];
    const float* wq = (const float*)d_in[1];
    const float* wk = (const float*)d_in[2];
    const float* wv = (const float*)d_in[3];
    const float* wo = (const float*)d_in[4];
    float* out = (float*)d_out;

    u16* ws  = (u16*)d_ws;
    u16* xb  = ws;                             // 4M : x bf16
    u16* Wt  = xb  + (size_t)4 * 1024 * 1024;  // 4M : 4 transposed weights
    u16* Qb  = Wt  + (size_t)4 * 1024 * 1024;  // 4M : Q [B,H,S,D] (pre-scaled)
    u16* Kb  = Qb  + (size_t)4 * 1024 * 1024;  // 4M : K [B,H,S,D]
    u16* Vtb = Kb  + (size_t)4 * 1024 * 1024;  // 4M : V^T [B,H,D,S]
    u16* ctx = Vtb + (size_t)4 * 1024 * 1024;  // 4M : ctx [B,S,E]

    prep_kernel<<<dim3(32, 32, 8), dim3(256), 0, stream>>>(x, wq, wk, wv, wo, xb, Wt);
    gemm_proj_kernel<<<dim3(8, 32, 3), dim3(256), 0, stream>>>(xb, Wt, Qb, Kb, Vtb);
    attn_kernel<<<dim3(8, 32), dim3(256), 0, stream>>>(Qb, Kb, Vtb, ctx);
    gemm_out_kernel<<<dim3(16, 32), dim3(256), 0, stream>>>(ctx, Wt + (size_t)3 * 1024 * 1024, out);
}

// Round 9
// 179.814 us; speedup vs baseline: 1.0787x; 1.0787x over previous
//
#include <hip/hip_runtime.h>
#include <hip/hip_bf16.h>

#define S_LEN 2048
#define EMB   1024
#define NH    16
#define HD    64
#define BATCH 2
#define MROWS (BATCH * S_LEN)   // 4096

typedef __attribute__((ext_vector_type(8))) short short8;   // 8 bf16 = 4 VGPR
typedef __attribute__((ext_vector_type(4))) float float4v;  // 4 fp32

#define MFMA16(a, b, c) __builtin_amdgcn_mfma_f32_16x16x32_bf16((a), (b), (c), 0, 0, 0)

typedef unsigned short u16;
typedef unsigned int   u32;

__device__ __forceinline__ u16 f2bf(float f) {
    union { float f; u32 u; } v; v.f = f;
    u32 u = v.u;
    return (u16)((u + 0x7fffu + ((u >> 16) & 1u)) >> 16);  // RNE
}

// packed fp32x2 -> bf16x2 (HW RNE on gfx950; fallback manual)
#if __has_builtin(__builtin_amdgcn_cvt_pk_bf16_f32)
typedef __attribute__((ext_vector_type(2))) __bf16 bfx2;
__device__ __forceinline__ u32 pkbf(float a, float b) {
    union { bfx2 v; u32 u; } c;
    c.v = __builtin_amdgcn_cvt_pk_bf16_f32(a, b);
    return c.u;
}
#else
__device__ __forceinline__ u32 pkbf(float a, float b) {
    return (u32)f2bf(a) | ((u32)f2bf(b) << 16);
}
#endif

#if __has_builtin(__builtin_amdgcn_exp2f)
#define EXP2(x) __builtin_amdgcn_exp2f(x)
#else
#define EXP2(x) exp2f(x)
#endif

// async 16B global->LDS (lds dest = wave-uniform base + lane*16)
typedef __attribute__((address_space(3))) unsigned char lds_u8;
typedef __attribute__((address_space(1))) const unsigned char glb_u8;
__device__ __forceinline__ void async_copy16(const void* g, void* l) {
    __builtin_amdgcn_global_load_lds((glb_u8*)g, (lds_u8*)l, 16, 0, 0);
}

// ---------------------------------------------------------------------------
// K0: fused prologue. z=0..3: convert+transpose weight z (Wq pre-scaled by
// 0.125*log2e so QK scores exit the MFMA in exp2 domain). z=4..7: x -> bf16.
// ---------------------------------------------------------------------------
__global__ __launch_bounds__(256) void prep_kernel(
    const float* __restrict__ x,
    const float* __restrict__ W0, const float* __restrict__ W1,
    const float* __restrict__ W2, const float* __restrict__ W3,
    u16* __restrict__ xb, u16* __restrict__ Wt) {
    const int z = blockIdx.z;
    const int tid = threadIdx.x;
    if (z >= 4) {
        int i = ((((z - 4) * 1024) + blockIdx.y * 32 + blockIdx.x) * 256 + tid) * 4;
        float4 f = *(const float4*)(x + i);
        uint2 o; o.x = pkbf(f.x, f.y); o.y = pkbf(f.z, f.w);
        *(uint2*)(xb + i) = o;
        return;
    }
    const float* W = (z == 0) ? W0 : (z == 1) ? W1 : (z == 2) ? W2 : W3;
    u16* dst = Wt + (size_t)z * EMB * EMB;
    const float sc = (z == 0) ? 0.18033688011112042f : 1.0f;
    __shared__ float tile[32][33];
    int c0 = blockIdx.x * 32, r0 = blockIdx.y * 32;
    int tx = tid & 31, ty = tid >> 5;
#pragma unroll
    for (int i = 0; i < 4; ++i)
        tile[ty + 8 * i][tx] = W[(size_t)(r0 + ty + 8 * i) * EMB + c0 + tx];
    __syncthreads();
#pragma unroll
    for (int i = 0; i < 4; ++i)
        dst[(size_t)(c0 + ty + 8 * i) * EMB + r0 + tx] = f2bf(tile[tx][ty + 8 * i] * sc);
}

// ---------------------------------------------------------------------------
// GEMM core (128x128): BK=32, depth-1 LDS double-buffer, xor swizzle
// s(row)=(row>>1)&3 (2-way on banks = free). Prefetch before MFMAs.
// ---------------------------------------------------------------------------
#define GEMM_STEP(B, KN)                                                                       \
    {                                                                                           \
        short8 a[4], b[4];                                                                      \
        _Pragma("unroll")                                                                       \
        for (int i = 0; i < 4; ++i) a[i] = *(const short8*)&As[B][wm * 64 + i * 16 + l15][ca];  \
        _Pragma("unroll")                                                                       \
        for (int j = 0; j < 4; ++j) b[j] = *(const short8*)&Bs[B][wn * 64 + j * 16 + l15][ca];  \
        if ((KN) < EMB) {                                                                       \
            for (int wl = wid; wl < 8; wl += 4) {                                               \
                async_copy16(&Ag[(size_t)(m0 + wl * 16 + rr) * EMB + (KN) + cc], &As[B ^ 1][wl * 16][0]); \
                async_copy16(&Bg[(size_t)(n0 + wl * 16 + rr) * EMB + (KN) + cc], &Bs[B ^ 1][wl * 16][0]); \
            }                                                                                   \
        }                                                                                       \
        _Pragma("unroll")                                                                       \
        for (int i = 0; i < 4; ++i)                                                             \
            _Pragma("unroll")                                                                   \
            for (int j = 0; j < 4; ++j)                                                         \
                acc[i][j] = MFMA16(a[i], b[j], acc[i][j]);                                      \
        __syncthreads();                                                                        \
    }

#define GEMM_CORE(A_, B_)                                                                      \
    const int tid = threadIdx.x;                                                                \
    const int lane = tid & 63, wid = tid >> 6;                                                  \
    const int wm = wid >> 1, wn = wid & 1;                                                      \
    const int l15 = lane & 15, lq = lane >> 4;                                                  \
    const int m0 = blockIdx.y * 128, n0 = blockIdx.x * 128;                                     \
    const u16* Ag = (A_);                                                                       \
    const u16* Bg = (B_);                                                                       \
    __shared__ u16 As[2][128][32];                                                              \
    __shared__ u16 Bs[2][128][32];                                                              \
    float4v acc[4][4] = {};                                                                     \
    const int rr = lane >> 2;                                                                   \
    const int cc = ((lane & 3) ^ ((rr >> 1) & 3)) * 8;                                          \
    const int ca = (lq ^ ((l15 >> 1) & 3)) * 8;                                                 \
    for (int wl = wid; wl < 8; wl += 4) {                                                       \
        async_copy16(&Ag[(size_t)(m0 + wl * 16 + rr) * EMB + cc], &As[0][wl * 16][0]);          \
        async_copy16(&Bg[(size_t)(n0 + wl * 16 + rr) * EMB + cc], &Bs[0][wl * 16][0]);          \
    }                                                                                           \
    __syncthreads();                                                                            \
    for (int k0 = 0; k0 < EMB; k0 += 64) {                                                      \
        GEMM_STEP(0, k0 + 32)                                                                   \
        GEMM_STEP(1, k0 + 64)                                                                   \
    }

// K2: fused 3-projection GEMM: z=0 Q[B,H,S,D], z=1 K[B,H,S,D], z=2 V^T[B,H,D,S]
__global__ __launch_bounds__(256) void gemm_proj_kernel(
    const u16* __restrict__ A, const u16* __restrict__ WtAll,
    u16* __restrict__ Qb, u16* __restrict__ Kb, u16* __restrict__ Vtb) {
    const int z = blockIdx.z;
    const u16* Wt = WtAll + (size_t)z * EMB * EMB;
    GEMM_CORE(A, Wt)
#pragma unroll
    for (int i = 0; i < 4; ++i)
#pragma unroll
        for (int j = 0; j < 4; ++j) {
            int mb = m0 + wm * 64 + i * 16 + lq * 4;      // 4 consecutive m
            int n  = n0 + wn * 64 + j * 16 + l15;
            int b_ = mb >> 11, s = mb & 2047;
            int h = n >> 6, d = n & 63;
            if (z == 2) {
                uint2 pv;
                pv.x = pkbf(acc[i][j][0], acc[i][j][1]);
                pv.y = pkbf(acc[i][j][2], acc[i][j][3]);
                *(uint2*)&Vtb[(((size_t)(b_ * NH + h) * HD + d) * S_LEN) + s] = pv;
            } else {
                u16* dst = (z == 1) ? Kb : Qb;
#pragma unroll
                for (int r = 0; r < 4; ++r)
                    dst[(((size_t)(b_ * NH + h) * S_LEN + s + r) * HD) + d] = f2bf(acc[i][j][r]);
            }
        }
}

// ---------------------------------------------------------------------------
// K4: output GEMM -> fp32. 128m x 64n tiles: grid (16,32) = 512 blocks.
// ---------------------------------------------------------------------------
__global__ __launch_bounds__(256) void gemm_out_kernel(
    const u16* __restrict__ A, const u16* __restrict__ Wt, float* __restrict__ out) {
    const int tid = threadIdx.x;
    const int lane = tid & 63, wid = tid >> 6;
    const int wm = wid >> 1, wn = wid & 1;
    const int l15 = lane & 15, lq = lane >> 4;
    const int m0 = blockIdx.y * 128, n0 = blockIdx.x * 64;
    __shared__ u16 As[2][128][32];
    __shared__ u16 Bs[2][64][32];
    float4v acc[4][2] = {};
    const int rr = lane >> 2;
    const int cc = ((lane & 3) ^ ((rr >> 1) & 3)) * 8;
    const int ca = (lq ^ ((l15 >> 1) & 3)) * 8;

#define GO_STAGE(B, KN)                                                                        \
    {                                                                                           \
        for (int wl = wid; wl < 8; wl += 4)                                                     \
            async_copy16(&A[(size_t)(m0 + wl * 16 + rr) * EMB + (KN) + cc], &As[B][wl * 16][0]);\
        async_copy16(&Wt[(size_t)(n0 + wid * 16 + rr) * EMB + (KN) + cc], &Bs[B][wid * 16][0]); \
    }
#define GO_STEP(B, KN)                                                                         \
    {                                                                                           \
        short8 a[4], b[2];                                                                      \
        _Pragma("unroll")                                                                       \
        for (int i = 0; i < 4; ++i) a[i] = *(const short8*)&As[B][wm * 64 + i * 16 + l15][ca];  \
        _Pragma("unroll")                                                                       \
        for (int j = 0; j < 2; ++j) b[j] = *(const short8*)&Bs[B][wn * 32 + j * 16 + l15][ca];  \
        if ((KN) < EMB) GO_STAGE(B ^ 1, KN)                                                     \
        _Pragma("unroll")                                                                       \
        for (int i = 0; i < 4; ++i)                                                             \
            _Pragma("unroll")                                                                   \
            for (int j = 0; j < 2; ++j)                                                         \
                acc[i][j] = MFMA16(a[i], b[j], acc[i][j]);                                      \
        __syncthreads();                                                                        \
    }

    GO_STAGE(0, 0)
    __syncthreads();
    for (int k0 = 0; k0 < EMB; k0 += 64) {
        GO_STEP(0, k0 + 32)
        GO_STEP(1, k0 + 64)
    }
#pragma unroll
    for (int i = 0; i < 4; ++i)
#pragma unroll
        for (int j = 0; j < 2; ++j)
#pragma unroll
            for (int r = 0; r < 4; ++r) {
                int m = m0 + wm * 64 + i * 16 + lq * 4 + r;
                int n = n0 + wn * 32 + j * 16 + l15;
                out[(size_t)m * EMB + n] = acc[i][j][r];
            }
}

// ---------------------------------------------------------------------------
// K3: flash attention (causal), S^T = K*Q^T, fixed-shift softmax (m=0).
// SINGLETON blocks, 3/CU: one q-tile (64 rows) per block, grid (bh=32 x
// rank=32) = 1024 blocks. LDS 41.5 KB -> 3 blocks/CU = 12 waves/CU, and
// barriers of different blocks interleave (R8 lesson: co-resident
// INDEPENDENT blocks, not per-wave ILP, is what fills stalls).
// Global LPT: qt = 31 - blockIdx.y with bh on x (fastest) -> all 32-unit
// blocks dispatch first device-wide; 1-unit blocks backfill the tail.
// Lean loop: pre-scaled Wq (exp2-domain scores), fixed-shift softmax (no
// max/rescale/shuffles), MFMA ones-column l-sum, HW packed bf16.
// ---------------------------------------------------------------------------
#define ATTN_STAGE(B, T)                                                                       \
    {                                                                                           \
        int kv0s = (T) * 64;                                                                    \
        for (int wl = wid; wl < 8; wl += 4) {                                                   \
            async_copy16(&Kb[(size_t)(kv0s + wl * 8 + rr8) * HD + cc8], &Ks[B][wl * 8][0]);     \
            async_copy16(&Vb[(size_t)(wl * 8 + rr8) * S_LEN + kv0s + cc8], &Vs[B][wl * 8][0]);  \
        }                                                                                       \
    }

// QK + mask + exp2 + pack + write (no drain, no PV)
#define ATTN_QKSM(KF, T, QF, PS, QW)                                                           \
    {                                                                                           \
        const int kv0 = (T) * 64;                                                               \
        float4v sc[4];                                                                          \
        _Pragma("unroll")                                                                       \
        for (int nt = 0; nt < 4; ++nt) {                                                        \
            float4v c4 = {};                                                                    \
            c4 = MFMA16(KF[nt][0], QF[0], c4);                                                  \
            c4 = MFMA16(KF[nt][1], QF[1], c4);                                                  \
            sc[nt] = c4;                                                                        \
        }                                                                                       \
        if (kv0 + 63 > (QW)) {                                                                  \
            const int qi = (QW) + l15;                                                          \
            _Pragma("unroll")                                                                   \
            for (int nt = 0; nt < 4; ++nt)                                                      \
                _Pragma("unroll")                                                               \
                for (int r = 0; r < 4; ++r)                                                     \
                    if (kv0 + nt * 16 + lq * 4 + r > qi) sc[nt][r] = -__builtin_inff();         \
        }                                                                                       \
        _Pragma("unroll")                                                                       \
        for (int nt = 0; nt < 4; ++nt) {                                                        \
            float p0 = EXP2(sc[nt][0]);                                                         \
            float p1 = EXP2(sc[nt][1]);                                                         \
            float p2 = EXP2(sc[nt][2]);                                                         \
            float p3 = EXP2(sc[nt][3]);                                                         \
            uint2 pk;                                                                           \
            pk.x = pkbf(p0, p1);                                                                \
            pk.y = pkbf(p2, p3);                                                                \
            *(uint2*)&PS[wid][l15][nt * 16 + lq * 4] = pk;                                      \
        }                                                                                       \
    }

#define ATTN_PV(PS, VF, OO, LS)                                                                \
    {                                                                                           \
        _Pragma("unroll")                                                                       \
        for (int kk = 0; kk < 2; ++kk) {                                                        \
            short8 pf = *(const short8*)&PS[wid][l15][kk * 32 + lq * 8];                        \
            _Pragma("unroll")                                                                   \
            for (int nd = 0; nd < 4; ++nd)                                                      \
                OO[nd] = MFMA16(pf, VF[kk][nd], OO[nd]);                                        \
            LS = MFMA16(pf, ones8, LS);                                                         \
        }                                                                                       \
    }

#define ATTN_TILE(B, T)                                                                        \
    {                                                                                           \
        if ((T) + 1 < ntiles) ATTN_STAGE(B ^ 1, (T) + 1)                                        \
        short8 kf[4][2];                                                                        \
        _Pragma("unroll")                                                                       \
        for (int nt = 0; nt < 4; ++nt) {                                                        \
            int r_ = nt * 16 + l15;                                                             \
            int sw = r_ & 7;                                                                    \
            kf[nt][0] = *(const short8*)&Ks[B][r_][(lq ^ sw) * 8];                              \
            kf[nt][1] = *(const short8*)&Ks[B][r_][((lq + 4) ^ sw) * 8];                        \
        }                                                                                       \
        ATTN_QKSM(kf, T, qf, Ps, qw)                                                            \
        short8 vf[2][4];                                                                        \
        _Pragma("unroll")                                                                       \
        for (int kk = 0; kk < 2; ++kk)                                                          \
            _Pragma("unroll")                                                                   \
            for (int nd = 0; nd < 4; ++nd) {                                                    \
                int d = nd * 16 + l15;                                                          \
                vf[kk][nd] = *(const short8*)&Vs[B][d][((kk * 4 + lq) ^ (d & 7)) * 8];          \
            }                                                                                   \
        asm volatile("s_waitcnt lgkmcnt(0)" ::: "memory");                                      \
        ATTN_PV(Ps, vf, O, ls)                                                                  \
        __syncthreads();                                                                        \
    }

#define ATTN_EPI(OO, LS, Q0)                                                                   \
    {                                                                                           \
        _Pragma("unroll")                                                                       \
        for (int r = 0; r < 4; ++r) {                                                           \
            float lr = 1.f / LS[r];                                                             \
            int s = (Q0) + wid * 16 + lq * 4 + r;                                               \
            size_t base = ((size_t)b * S_LEN + s) * EMB + h * HD;                               \
            _Pragma("unroll")                                                                   \
            for (int nd = 0; nd < 4; ++nd)                                                      \
                ctx[base + nd * 16 + l15] = f2bf(OO[nd][r] * lr);                               \
        }                                                                                       \
    }

__global__ __launch_bounds__(256) void attn_kernel(
    const u16* __restrict__ Q, const u16* __restrict__ K,
    const u16* __restrict__ Vt, u16* __restrict__ ctx) {
    const int tid = threadIdx.x;
    const int lane = tid & 63, wid = tid >> 6;
    const int l15 = lane & 15, lq = lane >> 4;
    const int bh = blockIdx.x;               // x fastest: heavy ranks first
    const int b = bh >> 4, h = bh & 15;
    const int qt = 31 - (int)blockIdx.y;     // global heavy-first (LPT)
    const int q0 = qt * 64;
    const int qw = q0 + wid * 16;

    const u16* Qb = Q + (size_t)bh * S_LEN * HD;
    const u16* Kb = K + (size_t)bh * S_LEN * HD;
    const u16* Vb = Vt + (size_t)bh * HD * S_LEN;

    __shared__ u16 Ks[2][64][64];   // [kv][d], xor-swizzled chunks (16 KB)
    __shared__ u16 Vs[2][64][64];   // [d][kv], xor-swizzled chunks (16 KB)
    __shared__ u16 Ps[4][16][68];   // per-wave P [q][kv], pad +4 (8.5 KB)

    const int rr8 = lane >> 3;
    const int cc8 = ((lane & 7) ^ rr8) * 8;  // s(row)=row&7

    // ones column for MFMA row-sum (bf16 1.0 = 0x3F80)
    short8 ones8;
#pragma unroll
    for (int i = 0; i < 8; ++i) ones8[i] = (short)0x3F80;

    // Q fragments (B-operand layout: lane n=l15 q-row, k=lq*8+j)
    short8 qf[2];
#pragma unroll
    for (int ks = 0; ks < 2; ++ks)
        qf[ks] = *(const short8*)&Qb[(size_t)(qw + l15) * HD + ks * 32 + lq * 8];

    float4v O[4] = {};
    float4v ls = {};

    const int ntiles = qt + 1;
    ATTN_STAGE(0, 0)
    __syncthreads();
    for (int t = 0; t < ntiles; t += 2) {
        ATTN_TILE(0, t)
        if (t + 1 < ntiles) ATTN_TILE(1, t + 1)
    }

    ATTN_EPI(O, ls, q0)
}

// ---------------------------------------------------------------------------
extern "C" void kernel_launch(void* const* d_in, const int* in_sizes, int n_in,
                              void* d_out, int out_size, void* d_ws, size_t ws_size,
                              hipStream_t stream) {
    const float* x  = (const float*)d_in[0];
    const float* wq = (const float*)d_in[1];
    const float* wk = (const float*)d_in[2];
    const float* wv = (const float*)d_in[3];
    const float* wo = (const float*)d_in[4];
    float* out = (float*)d_out;

    u16* ws  = (u16*)d_ws;
    u16* xb  = ws;                             // 4M : x bf16
    u16* Wt  = xb  + (size_t)4 * 1024 * 1024;  // 4M : 4 transposed weights
    u16* Qb  = Wt  + (size_t)4 * 1024 * 1024;  // 4M : Q [B,H,S,D] (pre-scaled)
    u16* Kb  = Qb  + (size_t)4 * 1024 * 1024;  // 4M : K [B,H,S,D]
    u16* Vtb = Kb  + (size_t)4 * 1024 * 1024;  // 4M : V^T [B,H,D,S]
    u16* ctx = Vtb + (size_t)4 * 1024 * 1024;  // 4M : ctx [B,S,E]

    prep_kernel<<<dim3(32, 32, 8), dim3(256), 0, stream>>>(x, wq, wk, wv, wo, xb, Wt);
    gemm_proj_kernel<<<dim3(8, 32, 3), dim3(256), 0, stream>>>(xb, Wt, Qb, Kb, Vtb);
    attn_kernel<<<dim3(32, 32), dim3(256), 0, stream>>>(Qb, Kb, Vtb, ctx);
    gemm_out_kernel<<<dim3(16, 32), dim3(256), 0, stream>>>(ctx, Wt + (size_t)3 * 1024 * 1024, out);
}

// Round 10
// 178.204 us; speedup vs baseline: 1.0885x; 1.0090x over previous
//
#include <hip/hip_runtime.h>
#include <hip/hip_bf16.h>

#define S_LEN 2048
#define EMB   1024
#define NH    16
#define HD    64
#define BATCH 2
#define MROWS (BATCH * S_LEN)   // 4096

typedef __attribute__((ext_vector_type(8))) short short8;   // 8 bf16 = 4 VGPR
typedef __attribute__((ext_vector_type(4))) float float4v;  // 4 fp32

#define MFMA16(a, b, c) __builtin_amdgcn_mfma_f32_16x16x32_bf16((a), (b), (c), 0, 0, 0)

typedef unsigned short u16;
typedef unsigned int   u32;

__device__ __forceinline__ u16 f2bf(float f) {
    union { float f; u32 u; } v; v.f = f;
    u32 u = v.u;
    return (u16)((u + 0x7fffu + ((u >> 16) & 1u)) >> 16);  // RNE
}

// packed fp32x2 -> bf16x2 (HW RNE on gfx950; fallback manual)
#if __has_builtin(__builtin_amdgcn_cvt_pk_bf16_f32)
typedef __attribute__((ext_vector_type(2))) __bf16 bfx2;
__device__ __forceinline__ u32 pkbf(float a, float b) {
    union { bfx2 v; u32 u; } c;
    c.v = __builtin_amdgcn_cvt_pk_bf16_f32(a, b);
    return c.u;
}
#else
__device__ __forceinline__ u32 pkbf(float a, float b) {
    return (u32)f2bf(a) | ((u32)f2bf(b) << 16);
}
#endif

#if __has_builtin(__builtin_amdgcn_exp2f)
#define EXP2(x) __builtin_amdgcn_exp2f(x)
#else
#define EXP2(x) exp2f(x)
#endif

// async 16B global->LDS (lds dest = wave-uniform base + lane*16)
typedef __attribute__((address_space(3))) unsigned char lds_u8;
typedef __attribute__((address_space(1))) const unsigned char glb_u8;
__device__ __forceinline__ void async_copy16(const void* g, void* l) {
    __builtin_amdgcn_global_load_lds((glb_u8*)g, (lds_u8*)l, 16, 0, 0);
}

// ---------------------------------------------------------------------------
// K0: fused prologue. z=0..3: convert+transpose weight z (Wq pre-scaled by
// 0.125*log2e so QK scores exit the MFMA in exp2 domain). z=4..7: x -> bf16.
// ---------------------------------------------------------------------------
__global__ __launch_bounds__(256) void prep_kernel(
    const float* __restrict__ x,
    const float* __restrict__ W0, const float* __restrict__ W1,
    const float* __restrict__ W2, const float* __restrict__ W3,
    u16* __restrict__ xb, u16* __restrict__ Wt) {
    const int z = blockIdx.z;
    const int tid = threadIdx.x;
    if (z >= 4) {
        int i = ((((z - 4) * 1024) + blockIdx.y * 32 + blockIdx.x) * 256 + tid) * 4;
        float4 f = *(const float4*)(x + i);
        uint2 o; o.x = pkbf(f.x, f.y); o.y = pkbf(f.z, f.w);
        *(uint2*)(xb + i) = o;
        return;
    }
    const float* W = (z == 0) ? W0 : (z == 1) ? W1 : (z == 2) ? W2 : W3;
    u16* dst = Wt + (size_t)z * EMB * EMB;
    const float sc = (z == 0) ? 0.18033688011112042f : 1.0f;
    __shared__ float tile[32][33];
    int c0 = blockIdx.x * 32, r0 = blockIdx.y * 32;
    int tx = tid & 31, ty = tid >> 5;
#pragma unroll
    for (int i = 0; i < 4; ++i)
        tile[ty + 8 * i][tx] = W[(size_t)(r0 + ty + 8 * i) * EMB + c0 + tx];
    __syncthreads();
#pragma unroll
    for (int i = 0; i < 4; ++i)
        dst[(size_t)(c0 + ty + 8 * i) * EMB + r0 + tx] = f2bf(tile[tx][ty + 8 * i] * sc);
}

// ---------------------------------------------------------------------------
// GEMM core (128x128): BK=32, depth-1 LDS double-buffer, xor swizzle
// s(row)=(row>>1)&3 (2-way on banks = free). Prefetch before MFMAs.
// ---------------------------------------------------------------------------
#define GEMM_STEP(B, KN)                                                                       \
    {                                                                                           \
        short8 a[4], b[4];                                                                      \
        _Pragma("unroll")                                                                       \
        for (int i = 0; i < 4; ++i) a[i] = *(const short8*)&As[B][wm * 64 + i * 16 + l15][ca];  \
        _Pragma("unroll")                                                                       \
        for (int j = 0; j < 4; ++j) b[j] = *(const short8*)&Bs[B][wn * 64 + j * 16 + l15][ca];  \
        if ((KN) < EMB) {                                                                       \
            for (int wl = wid; wl < 8; wl += 4) {                                               \
                async_copy16(&Ag[(size_t)(m0 + wl * 16 + rr) * EMB + (KN) + cc], &As[B ^ 1][wl * 16][0]); \
                async_copy16(&Bg[(size_t)(n0 + wl * 16 + rr) * EMB + (KN) + cc], &Bs[B ^ 1][wl * 16][0]); \
            }                                                                                   \
        }                                                                                       \
        _Pragma("unroll")                                                                       \
        for (int i = 0; i < 4; ++i)                                                             \
            _Pragma("unroll")                                                                   \
            for (int j = 0; j < 4; ++j)                                                         \
                acc[i][j] = MFMA16(a[i], b[j], acc[i][j]);                                      \
        __syncthreads();                                                                        \
    }

#define GEMM_CORE(A_, B_)                                                                      \
    const int tid = threadIdx.x;                                                                \
    const int lane = tid & 63, wid = tid >> 6;                                                  \
    const int wm = wid >> 1, wn = wid & 1;                                                      \
    const int l15 = lane & 15, lq = lane >> 4;                                                  \
    const int m0 = blockIdx.y * 128, n0 = blockIdx.x * 128;                                     \
    const u16* Ag = (A_);                                                                       \
    const u16* Bg = (B_);                                                                       \
    __shared__ u16 As[2][128][32];                                                              \
    __shared__ u16 Bs[2][128][32];                                                              \
    float4v acc[4][4] = {};                                                                     \
    const int rr = lane >> 2;                                                                   \
    const int cc = ((lane & 3) ^ ((rr >> 1) & 3)) * 8;                                          \
    const int ca = (lq ^ ((l15 >> 1) & 3)) * 8;                                                 \
    for (int wl = wid; wl < 8; wl += 4) {                                                       \
        async_copy16(&Ag[(size_t)(m0 + wl * 16 + rr) * EMB + cc], &As[0][wl * 16][0]);          \
        async_copy16(&Bg[(size_t)(n0 + wl * 16 + rr) * EMB + cc], &Bs[0][wl * 16][0]);          \
    }                                                                                           \
    __syncthreads();                                                                            \
    for (int k0 = 0; k0 < EMB; k0 += 64) {                                                      \
        GEMM_STEP(0, k0 + 32)                                                                   \
        GEMM_STEP(1, k0 + 64)                                                                   \
    }

// K2: fused 3-projection GEMM: z=0 Q[B,H,S,D], z=1 K[B,H,S,D], z=2 V^T[B,H,D,S]
__global__ __launch_bounds__(256) void gemm_proj_kernel(
    const u16* __restrict__ A, const u16* __restrict__ WtAll,
    u16* __restrict__ Qb, u16* __restrict__ Kb, u16* __restrict__ Vtb) {
    const int z = blockIdx.z;
    const u16* Wt = WtAll + (size_t)z * EMB * EMB;
    GEMM_CORE(A, Wt)
#pragma unroll
    for (int i = 0; i < 4; ++i)
#pragma unroll
        for (int j = 0; j < 4; ++j) {
            int mb = m0 + wm * 64 + i * 16 + lq * 4;      // 4 consecutive m
            int n  = n0 + wn * 64 + j * 16 + l15;
            int b_ = mb >> 11, s = mb & 2047;
            int h = n >> 6, d = n & 63;
            if (z == 2) {
                uint2 pv;
                pv.x = pkbf(acc[i][j][0], acc[i][j][1]);
                pv.y = pkbf(acc[i][j][2], acc[i][j][3]);
                *(uint2*)&Vtb[(((size_t)(b_ * NH + h) * HD + d) * S_LEN) + s] = pv;
            } else {
                u16* dst = (z == 1) ? Kb : Qb;
#pragma unroll
                for (int r = 0; r < 4; ++r)
                    dst[(((size_t)(b_ * NH + h) * S_LEN + s + r) * HD) + d] = f2bf(acc[i][j][r]);
            }
        }
}

// ---------------------------------------------------------------------------
// K4: output GEMM -> fp32. 128m x 64n tiles: grid (16,32) = 512 blocks.
// ---------------------------------------------------------------------------
__global__ __launch_bounds__(256) void gemm_out_kernel(
    const u16* __restrict__ A, const u16* __restrict__ Wt, float* __restrict__ out) {
    const int tid = threadIdx.x;
    const int lane = tid & 63, wid = tid >> 6;
    const int wm = wid >> 1, wn = wid & 1;
    const int l15 = lane & 15, lq = lane >> 4;
    const int m0 = blockIdx.y * 128, n0 = blockIdx.x * 64;
    __shared__ u16 As[2][128][32];
    __shared__ u16 Bs[2][64][32];
    float4v acc[4][2] = {};
    const int rr = lane >> 2;
    const int cc = ((lane & 3) ^ ((rr >> 1) & 3)) * 8;
    const int ca = (lq ^ ((l15 >> 1) & 3)) * 8;

#define GO_STAGE(B, KN)                                                                        \
    {                                                                                           \
        for (int wl = wid; wl < 8; wl += 4)                                                     \
            async_copy16(&A[(size_t)(m0 + wl * 16 + rr) * EMB + (KN) + cc], &As[B][wl * 16][0]);\
        async_copy16(&Wt[(size_t)(n0 + wid * 16 + rr) * EMB + (KN) + cc], &Bs[B][wid * 16][0]); \
    }
#define GO_STEP(B, KN)                                                                         \
    {                                                                                           \
        short8 a[4], b[2];                                                                      \
        _Pragma("unroll")                                                                       \
        for (int i = 0; i < 4; ++i) a[i] = *(const short8*)&As[B][wm * 64 + i * 16 + l15][ca];  \
        _Pragma("unroll")                                                                       \
        for (int j = 0; j < 2; ++j) b[j] = *(const short8*)&Bs[B][wn * 32 + j * 16 + l15][ca];  \
        if ((KN) < EMB) GO_STAGE(B ^ 1, KN)                                                     \
        _Pragma("unroll")                                                                       \
        for (int i = 0; i < 4; ++i)                                                             \
            _Pragma("unroll")                                                                   \
            for (int j = 0; j < 2; ++j)                                                         \
                acc[i][j] = MFMA16(a[i], b[j], acc[i][j]);                                      \
        __syncthreads();                                                                        \
    }

    GO_STAGE(0, 0)
    __syncthreads();
    for (int k0 = 0; k0 < EMB; k0 += 64) {
        GO_STEP(0, k0 + 32)
        GO_STEP(1, k0 + 64)
    }
#pragma unroll
    for (int i = 0; i < 4; ++i)
#pragma unroll
        for (int j = 0; j < 2; ++j)
#pragma unroll
            for (int r = 0; r < 4; ++r) {
                int m = m0 + wm * 64 + i * 16 + lq * 4 + r;
                int n = n0 + wn * 32 + j * 16 + l15;
                out[(size_t)m * EMB + n] = acc[i][j][r];
            }
}

// ---------------------------------------------------------------------------
// K3: flash attention (causal), S^T = K*Q^T, fixed-shift softmax (m=0).
// Singleton q-tile blocks + global LPT (R9). NEW: Ps stores via 16B-chunk
// XOR swizzle (chunk ^= l15&7) instead of +4 padding -> Ps = 8 KB and total
// LDS EXACTLY 40960 B = 160 KiB / 4 -> 4 blocks/CU = 16 waves/CU (was 3).
// Residency is the proven scaling axis (R8: 1/CU = 65us, R9: 3/CU = 43.5us).
// Both Ps phases are 2-way bank aliasing (free, m136).
// ---------------------------------------------------------------------------
#define ATTN_STAGE(B, T)                                                                       \
    {                                                                                           \
        int kv0s = (T) * 64;                                                                    \
        for (int wl = wid; wl < 8; wl += 4) {                                                   \
            async_copy16(&Kb[(size_t)(kv0s + wl * 8 + rr8) * HD + cc8], &Ks[B][wl * 8][0]);     \
            async_copy16(&Vb[(size_t)(wl * 8 + rr8) * S_LEN + kv0s + cc8], &Vs[B][wl * 8][0]);  \
        }                                                                                       \
    }

// QK + mask + exp2 + pack + swizzled Ps write (no drain, no PV)
#define ATTN_QKSM(KF, T, QF, PS, QW)                                                           \
    {                                                                                           \
        const int kv0 = (T) * 64;                                                               \
        float4v sc[4];                                                                          \
        _Pragma("unroll")                                                                       \
        for (int nt = 0; nt < 4; ++nt) {                                                        \
            float4v c4 = {};                                                                    \
            c4 = MFMA16(KF[nt][0], QF[0], c4);                                                  \
            c4 = MFMA16(KF[nt][1], QF[1], c4);                                                  \
            sc[nt] = c4;                                                                        \
        }                                                                                       \
        if (kv0 + 63 > (QW)) {                                                                  \
            const int qi = (QW) + l15;                                                          \
            _Pragma("unroll")                                                                   \
            for (int nt = 0; nt < 4; ++nt)                                                      \
                _Pragma("unroll")                                                               \
                for (int r = 0; r < 4; ++r)                                                     \
                    if (kv0 + nt * 16 + lq * 4 + r > qi) sc[nt][r] = -__builtin_inff();         \
        }                                                                                       \
        _Pragma("unroll")                                                                       \
        for (int nt = 0; nt < 4; ++nt) {                                                        \
            float p0 = EXP2(sc[nt][0]);                                                         \
            float p1 = EXP2(sc[nt][1]);                                                         \
            float p2 = EXP2(sc[nt][2]);                                                         \
            float p3 = EXP2(sc[nt][3]);                                                         \
            uint2 pk;                                                                           \
            pk.x = pkbf(p0, p1);                                                                \
            pk.y = pkbf(p2, p3);                                                                \
            /* chunk-space write: chunk = nt*2+(lq>>1), sub-8B = lq&1, ^swp */                  \
            *(uint2*)((char*)&PS[wid][l15][0] +                                                 \
                      (((nt * 2 + (lq >> 1)) ^ swp) * 16 + (lq & 1) * 8)) = pk;                 \
        }                                                                                       \
    }

#define ATTN_PV(PS, VF, OO, LS)                                                                \
    {                                                                                           \
        _Pragma("unroll")                                                                       \
        for (int kk = 0; kk < 2; ++kk) {                                                        \
            /* chunk-space read: chunk = kk*4+lq, ^swp (same mapping) */                        \
            short8 pf = *(const short8*)((const char*)&PS[wid][l15][0] +                        \
                                         (((kk * 4 + lq) ^ swp) * 16));                         \
            _Pragma("unroll")                                                                   \
            for (int nd = 0; nd < 4; ++nd)                                                      \
                OO[nd] = MFMA16(pf, VF[kk][nd], OO[nd]);                                        \
            LS = MFMA16(pf, ones8, LS);                                                         \
        }                                                                                       \
    }

#define ATTN_TILE(B, T)                                                                        \
    {                                                                                           \
        if ((T) + 1 < ntiles) ATTN_STAGE(B ^ 1, (T) + 1)                                        \
        short8 kf[4][2];                                                                        \
        _Pragma("unroll")                                                                       \
        for (int nt = 0; nt < 4; ++nt) {                                                        \
            int r_ = nt * 16 + l15;                                                             \
            int sw = r_ & 7;                                                                    \
            kf[nt][0] = *(const short8*)&Ks[B][r_][(lq ^ sw) * 8];                              \
            kf[nt][1] = *(const short8*)&Ks[B][r_][((lq + 4) ^ sw) * 8];                        \
        }                                                                                       \
        ATTN_QKSM(kf, T, qf, Ps, qw)                                                            \
        short8 vf[2][4];                                                                        \
        _Pragma("unroll")                                                                       \
        for (int kk = 0; kk < 2; ++kk)                                                          \
            _Pragma("unroll")                                                                   \
            for (int nd = 0; nd < 4; ++nd) {                                                    \
                int d = nd * 16 + l15;                                                          \
                vf[kk][nd] = *(const short8*)&Vs[B][d][((kk * 4 + lq) ^ (d & 7)) * 8];          \
            }                                                                                   \
        asm volatile("s_waitcnt lgkmcnt(0)" ::: "memory");                                      \
        ATTN_PV(Ps, vf, O, ls)                                                                  \
        __syncthreads();                                                                        \
    }

#define ATTN_EPI(OO, LS, Q0)                                                                   \
    {                                                                                           \
        _Pragma("unroll")                                                                       \
        for (int r = 0; r < 4; ++r) {                                                           \
            float lr = 1.f / LS[r];                                                             \
            int s = (Q0) + wid * 16 + lq * 4 + r;                                               \
            size_t base = ((size_t)b * S_LEN + s) * EMB + h * HD;                               \
            _Pragma("unroll")                                                                   \
            for (int nd = 0; nd < 4; ++nd)                                                      \
                ctx[base + nd * 16 + l15] = f2bf(OO[nd][r] * lr);                               \
        }                                                                                       \
    }

__global__ __launch_bounds__(256) void attn_kernel(
    const u16* __restrict__ Q, const u16* __restrict__ K,
    const u16* __restrict__ Vt, u16* __restrict__ ctx) {
    const int tid = threadIdx.x;
    const int lane = tid & 63, wid = tid >> 6;
    const int l15 = lane & 15, lq = lane >> 4;
    const int bh = blockIdx.x;               // x fastest: heavy ranks first
    const int b = bh >> 4, h = bh & 15;
    const int qt = 31 - (int)blockIdx.y;     // global heavy-first (LPT)
    const int q0 = qt * 64;
    const int qw = q0 + wid * 16;

    const u16* Qb = Q + (size_t)bh * S_LEN * HD;
    const u16* Kb = K + (size_t)bh * S_LEN * HD;
    const u16* Vb = Vt + (size_t)bh * HD * S_LEN;

    __shared__ u16 Ks[2][64][64];   // [kv][d], xor-swizzled chunks (16 KB)
    __shared__ u16 Vs[2][64][64];   // [d][kv], xor-swizzled chunks (16 KB)
    __shared__ u16 Ps[4][16][64];   // per-wave P, chunk-swizzled (8 KB)
    // total LDS = 40960 B exactly -> 4 blocks/CU

    const int rr8 = lane >> 3;
    const int cc8 = ((lane & 7) ^ rr8) * 8;  // s(row)=row&7
    const int swp = l15 & 7;                 // Ps chunk swizzle key

    // ones column for MFMA row-sum (bf16 1.0 = 0x3F80)
    short8 ones8;
#pragma unroll
    for (int i = 0; i < 8; ++i) ones8[i] = (short)0x3F80;

    // Q fragments (B-operand layout: lane n=l15 q-row, k=lq*8+j)
    short8 qf[2];
#pragma unroll
    for (int ks = 0; ks < 2; ++ks)
        qf[ks] = *(const short8*)&Qb[(size_t)(qw + l15) * HD + ks * 32 + lq * 8];

    float4v O[4] = {};
    float4v ls = {};

    const int ntiles = qt + 1;
    ATTN_STAGE(0, 0)
    __syncthreads();
    for (int t = 0; t < ntiles; t += 2) {
        ATTN_TILE(0, t)
        if (t + 1 < ntiles) ATTN_TILE(1, t + 1)
    }

    ATTN_EPI(O, ls, q0)
}

// ---------------------------------------------------------------------------
extern "C" void kernel_launch(void* const* d_in, const int* in_sizes, int n_in,
                              void* d_out, int out_size, void* d_ws, size_t ws_size,
                              hipStream_t stream) {
    const float* x  = (const float*)d_in[0];
    const float* wq = (const float*)d_in[1];
    const float* wk = (const float*)d_in[2];
    const float* wv = (const float*)d_in[3];
    const float* wo = (const float*)d_in[4];
    float* out = (float*)d_out;

    u16* ws  = (u16*)d_ws;
    u16* xb  = ws;                             // 4M : x bf16
    u16* Wt  = xb  + (size_t)4 * 1024 * 1024;  // 4M : 4 transposed weights
    u16* Qb  = Wt  + (size_t)4 * 1024 * 1024;  // 4M : Q [B,H,S,D] (pre-scaled)
    u16* Kb  = Qb  + (size_t)4 * 1024 * 1024;  // 4M : K [B,H,S,D]
    u16* Vtb = Kb  + (size_t)4 * 1024 * 1024;  // 4M : V^T [B,H,D,S]
    u16* ctx = Vtb + (size_t)4 * 1024 * 1024;  // 4M : ctx [B,S,E]

    prep_kernel<<<dim3(32, 32, 8), dim3(256), 0, stream>>>(x, wq, wk, wv, wo, xb, Wt);
    gemm_proj_kernel<<<dim3(8, 32, 3), dim3(256), 0, stream>>>(xb, Wt, Qb, Kb, Vtb);
    attn_kernel<<<dim3(32, 32), dim3(256), 0, stream>>>(Qb, Kb, Vtb, ctx);
    gemm_out_kernel<<<dim3(16, 32), dim3(256), 0, stream>>>(ctx, Wt + (size_t)3 * 1024 * 1024, out);
}